// Round 1
// baseline (578.413 us; speedup 1.0000x reference)
//
#include <hip/hip_runtime.h>

#define T_LEN 4096
#define KS    16

#define ALPHA_F 0.9048374180359595f
#define BETA_F  0.09516258196404048f
#define THETA_F 0.5f

// --- cross-lane max helpers ---------------------------------------------
template<int CTRL>
__device__ __forceinline__ float dpp_max(float v) {
  int r = __builtin_amdgcn_update_dpp(0, __float_as_int(v), CTRL, 0xF, 0xF, true);
  return fmaxf(v, __int_as_float(r));
}

__device__ __forceinline__ float swap16_max(float v) {
#if __has_builtin(__builtin_amdgcn_permlane16_swap)
  auto r = __builtin_amdgcn_permlane16_swap(__float_as_int(v), __float_as_int(v), false, false);
  return fmaxf(__int_as_float((int)r[0]), __int_as_float((int)r[1]));
#else
  return fmaxf(v, __shfl_xor(v, 16, 64));
#endif
}

__device__ __forceinline__ float swap32_max(float v) {
#if __has_builtin(__builtin_amdgcn_permlane32_swap)
  auto r = __builtin_amdgcn_permlane32_swap(__float_as_int(v), __float_as_int(v), false, false);
  return fmaxf(__int_as_float((int)r[0]), __int_as_float((int)r[1]));
#else
  return fmaxf(v, __shfl_xor(v, 32, 64));
#endif
}

__global__ __launch_bounds__(64, 1)
void convlif_wta_kernel(const float* __restrict__ x, const float* __restrict__ W,
                        float* __restrict__ out) {
  const int b    = blockIdx.x;
  const int lane = threadIdx.x;   // channel k

  __shared__ float tile[64][65];  // [k][t&63], +1 pad -> conflict-free both ways

  // per-lane conv weights W[k][0..15]
  float w[KS];
  {
    const float4* w4 = reinterpret_cast<const float4*>(W + lane * KS);
    #pragma unroll
    for (int q = 0; q < 4; ++q) {
      float4 a = w4[q];
      w[4*q+0] = a.x; w[4*q+1] = a.y; w[4*q+2] = a.z; w[4*q+3] = a.w;
    }
  }

  const float4* xv4 = reinterpret_cast<const float4*>(x + (size_t)b * T_LEN);

  // rolling x window: xw[j] = x[tb-15+j], j = 0..30 (x[<0] = 0)
  float xw[31];
  float v = 0.0f;

  for (int t0 = 0; t0 < T_LEN; t0 += 64) {
    #pragma unroll 1
    for (int c = 0; c < 4; ++c) {
      const int tb = t0 + 16 * c;
      if (tb == 0) {
        #pragma unroll
        for (int j = 0; j < 15; ++j) xw[j] = 0.0f;
      } else {
        #pragma unroll
        for (int j = 0; j < 15; ++j) xw[j] = xw[j + 16];
      }
      // wave-uniform loads of x[tb .. tb+15]
      #pragma unroll
      for (int q = 0; q < 4; ++q) {
        float4 a = xv4[(tb >> 2) + q];
        xw[15+4*q+0] = a.x; xw[15+4*q+1] = a.y;
        xw[15+4*q+2] = a.z; xw[15+4*q+3] = a.w;
      }

      #pragma unroll
      for (int i = 0; i < 16; ++i) {
        // causal conv for t = tb+i : u = sum_j W[k][j] * x[t-15+j]
        float u = w[0] * xw[i];
        #pragma unroll
        for (int j = 1; j < KS; ++j) u = fmaf(w[j], xw[i + j], u);

        // leak + input
        v = ALPHA_F * v + BETA_F * u;

        // 64-lane max (butterfly: DPP within row16, permlane swaps across)
        float m = v;
        m = dpp_max<0xB1>(m);   // xor1  (quad_perm 1,0,3,2)
        m = dpp_max<0x4E>(m);   // xor2  (quad_perm 2,3,0,1)
        m = dpp_max<0x141>(m);  // xor7  (row_half_mirror)
        m = dpp_max<0x140>(m);  // xor15 (row_mirror)
        m = swap16_max(m);      // 16<->16 within 32
        m = swap32_max(m);      // low32 <-> high32

        // winner = lowest lane with v == vmax (matches argmax tie-break)
        unsigned long long eq = __ballot(v == m);
        unsigned below = __builtin_amdgcn_mbcnt_hi(
            (unsigned)(eq >> 32),
            __builtin_amdgcn_mbcnt_lo((unsigned)eq, 0u));
        bool sp = (v == m) && (below == 0u) && (m >= THETA_F);

        tile[lane][(tb + i) & 63] = sp ? 1.0f : 0.0f;
        v = sp ? v - THETA_F : v;   // == v - s*theta exactly
      }
    }

    // flush 64 timesteps, coalesced along t
    float* ob = out + ((size_t)b * 64) * T_LEN + t0 + lane;
    #pragma unroll 8
    for (int r = 0; r < 64; ++r) {
      ob[(size_t)r * T_LEN] = tile[r][lane];
    }
  }
}

extern "C" void kernel_launch(void* const* d_in, const int* in_sizes, int n_in,
                              void* d_out, int out_size, void* d_ws, size_t ws_size,
                              hipStream_t stream) {
  const float* x   = (const float*)d_in[0];
  const float* W   = (const float*)d_in[1];
  float*       out = (float*)d_out;
  convlif_wta_kernel<<<dim3(256), dim3(64), 0, stream>>>(x, W, out);
}